// Round 4
// baseline (3275.894 us; speedup 1.0000x reference)
//
#include <hip/hip_runtime.h>

// Seq2Seq GRU: B=256, S=128, T=64, I=63, H=1024.
// Inputs fp32, OUTPUT FP32 (reference returns float32). All GEMMs use bf16
// hi+lo split emulation (3-term MFMA: ahi*bhi + ahi*blo + alo*bhi ~= fp32
// product) so the 128-step recurrence tracks the fp32 numpy reference.

typedef unsigned short u16;
typedef __attribute__((ext_vector_type(8))) short s8v;   // 8 x bf16 (4 VGPRs)
typedef __attribute__((ext_vector_type(4))) float f4v;   // MFMA acc
typedef __attribute__((ext_vector_type(4))) int  i4v;    // 16B copy unit

__device__ __forceinline__ float b2f(u16 u) {
    return __uint_as_float(((unsigned int)u) << 16);
}
__device__ __forceinline__ u16 f2b(float f) {   // round-to-nearest-even
    unsigned int x = __float_as_uint(f);
    unsigned int r = x + 0x7fffu + ((x >> 16) & 1u);
    return (u16)(r >> 16);
}
__device__ __forceinline__ float sigf(float x) {
    return 1.0f / (1.0f + __expf(-x));
}
__device__ __forceinline__ f4v mfma16(s8v a, s8v b, f4v c) {
    return __builtin_amdgcn_mfma_f32_16x16x32_bf16(a, b, c, 0, 0, 0);
}

// ---------------------------------------------------------------------------
__global__ void zero_ws(i4v* __restrict__ p, int n) {
    int i = blockIdx.x * blockDim.x + threadIdx.x;
    if (i < n) { i4v z = {0, 0, 0, 0}; p[i] = z; }
}

// fp32 -> bf16 hi+lo split
__global__ void conv_split(const float* __restrict__ s, u16* __restrict__ hi,
                           u16* __restrict__ lo, int n) {
    int i = blockIdx.x * blockDim.x + threadIdx.x;
    int st = gridDim.x * blockDim.x;
    for (; i < n; i += st) {
        float v = s[i];
        u16 h = f2b(v);
        hi[i] = h;
        lo[i] = f2b(v - b2f(h));
    }
}

// Wih (3072 x 63 fp32) -> padded (3072 x 64) hi+lo, col 63 = 0
__global__ void conv_wih_split_pad(const float* __restrict__ s,
                                   u16* __restrict__ hi, u16* __restrict__ lo) {
    int idx = blockIdx.x * blockDim.x + threadIdx.x;   // 0..196607
    int row = idx >> 6, col = idx & 63;
    float v = (col < 63) ? s[(size_t)row * 63 + col] : 0.f;
    u16 h = f2b(v);
    hi[idx] = h;
    lo[idx] = f2b(v - b2f(h));
}

// proj_W (63 x 1024 fp32) -> padded (64 x 1024) hi+lo, row 63 = 0
__global__ void conv_pw_split_pad(const float* __restrict__ s,
                                  u16* __restrict__ hi, u16* __restrict__ lo) {
    int idx = blockIdx.x * blockDim.x + threadIdx.x;   // 0..65535
    float v = (idx < 63 * 1024) ? s[idx] : 0.f;
    u16 h = f2b(v);
    hi[idx] = h;
    lo[idx] = f2b(v - b2f(h));
}

// ---------------------------------------------------------------------------
// MODE 0: one encoder GRU step.  h_out = GRU(x_s, h_in)   (grid 256 = 4m x 64j)
// MODE 1: gh_dec = enc_h @ dec_Whh^T + dec_bhh (fp32 out).
// All weight operands are pre-split bf16 hi+lo; h is stored as hi+lo.
template <int MODE>
__global__ __launch_bounds__(256, 1) void gru_gemm(
    const u16* __restrict__ WhhH, const u16* __restrict__ WhhL,
    const u16* __restrict__ WihH, const u16* __restrict__ WihL,
    const float* __restrict__ bih, const float* __restrict__ bhh,
    const float* __restrict__ xenc, int s,
    const u16* __restrict__ hin_hi, const u16* __restrict__ hin_lo,
    u16* __restrict__ hout_hi, u16* __restrict__ hout_lo,
    float* __restrict__ gh_out)
{
    __shared__ u16 WbH[48 * 264];  // Whh-hi chunk: 48 rows x 256 k (+8 pad)
    __shared__ u16 WbL[48 * 264];  // Whh-lo chunk
    __shared__ u16 XbH[64 * 72];   // x-hi tile
    __shared__ u16 XbL[64 * 72];   // x-lo tile
    __shared__ u16 WisH[48 * 72];  // Wih-hi slice
    __shared__ u16 WisL[48 * 72];  // Wih-lo slice

    const int tid  = threadIdx.x;
    const int lane = tid & 63;
    const int wave = tid >> 6;
    const int lrow = lane & 15;     // MFMA m/n index
    const int lk8  = lane >> 4;     // MFMA k-group
    const int mt = blockIdx.x & 3;
    const int jt = blockIdx.x >> 2;
    const int m0 = mt * 64;
    const int j0 = jt * 16;

    f4v acc_r  = {0.f, 0.f, 0.f, 0.f};
    f4v acc_z  = {0.f, 0.f, 0.f, 0.f};
    f4v acc_gn = {0.f, 0.f, 0.f, 0.f};   // gi_n (input side, MODE 0 only)
    f4v acc_hn = {0.f, 0.f, 0.f, 0.f};   // gh_n (hidden side)

    // ---- prefetch Whh chunk 0 (hi+lo) into registers
    i4v stgH[6], stgL[6];
    #pragma unroll
    for (int i = 0; i < 6; ++i) {
        int c16 = i * 256 + tid;
        int row = c16 >> 5, p16 = c16 & 31;
        int grow = (row >> 4) * 1024 + j0 + (row & 15);
        size_t off = (size_t)grow * 1024 + p16 * 8;
        stgH[i] = *(const i4v*)(WhhH + off);
        stgL[i] = *(const i4v*)(WhhL + off);
    }

    if constexpr (MODE == 0) {
        // stage x tile (fp32 -> hi+lo) and Wih slices
        {
            int row = tid >> 2, q = tid & 3;
            const float* xr = xenc + (size_t)(m0 + row) * 8064 + s * 63;
            #pragma unroll
            for (int ii = 0; ii < 16; ++ii) {
                int col = q * 16 + ii;
                float v = (col < 63) ? xr[col] : 0.f;
                u16 hh = f2b(v);
                XbH[row * 72 + col] = hh;
                XbL[row * 72 + col] = f2b(v - b2f(hh));
            }
            if (tid < 192) {
                int wr = tid >> 2, qq = tid & 3;
                int grow = (wr >> 4) * 1024 + j0 + (wr & 15);
                const u16* wpH = WihH + (size_t)grow * 64 + qq * 16;
                const u16* wpL = WihL + (size_t)grow * 64 + qq * 16;
                *(i4v*)&WisH[wr * 72 + qq * 16]     = *(const i4v*)wpH;
                *(i4v*)&WisH[wr * 72 + qq * 16 + 8] = *(const i4v*)(wpH + 8);
                *(i4v*)&WisL[wr * 72 + qq * 16]     = *(const i4v*)wpL;
                *(i4v*)&WisL[wr * 72 + qq * 16 + 8] = *(const i4v*)(wpL + 8);
            }
        }
        __syncthreads();
        // gi = x @ Wih^T  (K=64 padded), 3-term split
        #pragma unroll
        for (int ks = 0; ks < 2; ++ks) {
            int ao = ks * 32 + lk8 * 8;
            s8v ah = *(const s8v*)&XbH[(wave * 16 + lrow) * 72 + ao];
            s8v al = *(const s8v*)&XbL[(wave * 16 + lrow) * 72 + ao];
            s8v brh = *(const s8v*)&WisH[(lrow) * 72 + ao];
            s8v brl = *(const s8v*)&WisL[(lrow) * 72 + ao];
            s8v bzh = *(const s8v*)&WisH[(16 + lrow) * 72 + ao];
            s8v bzl = *(const s8v*)&WisL[(16 + lrow) * 72 + ao];
            s8v bnh = *(const s8v*)&WisH[(32 + lrow) * 72 + ao];
            s8v bnl = *(const s8v*)&WisL[(32 + lrow) * 72 + ao];
            acc_r  = mfma16(ah, brh, acc_r);
            acc_r  = mfma16(ah, brl, acc_r);
            acc_r  = mfma16(al, brh, acc_r);
            acc_z  = mfma16(ah, bzh, acc_z);
            acc_z  = mfma16(ah, bzl, acc_z);
            acc_z  = mfma16(al, bzh, acc_z);
            acc_gn = mfma16(ah, bnh, acc_gn);
            acc_gn = mfma16(ah, bnl, acc_gn);
            acc_gn = mfma16(al, bnh, acc_gn);
        }
    }

    // ---- store chunk 0 to LDS
    #pragma unroll
    for (int i = 0; i < 6; ++i) {
        int c16 = i * 256 + tid;
        int row = c16 >> 5, p16 = c16 & 31;
        *(i4v*)&WbH[row * 264 + p16 * 8] = stgH[i];
        *(i4v*)&WbL[row * 264 + p16 * 8] = stgL[i];
    }
    __syncthreads();

    // ---- h GEMM: gh = h @ Whh^T, 3-term hi/lo split on BOTH operands
    const size_t arow = (size_t)(m0 + wave * 16 + lrow) * 1024 + lk8 * 8;
    const u16* hp = hin_hi + arow;
    const u16* lp = hin_lo + arow;

    for (int c = 0; c < 4; ++c) {
        if (c < 3) {   // prefetch next chunk into registers
            #pragma unroll
            for (int i = 0; i < 6; ++i) {
                int c16 = i * 256 + tid;
                int row = c16 >> 5, p16 = c16 & 31;
                int grow = (row >> 4) * 1024 + j0 + (row & 15);
                size_t off = (size_t)grow * 1024 + (c + 1) * 256 + p16 * 8;
                stgH[i] = *(const i4v*)(WhhH + off);
                stgL[i] = *(const i4v*)(WhhL + off);
            }
        }
        #pragma unroll
        for (int ks = 0; ks < 8; ++ks) {
            int kk = c * 256 + ks * 32;
            int bo = ks * 32 + lk8 * 8;
            s8v ahi = *(const s8v*)(hp + kk);
            s8v alo = *(const s8v*)(lp + kk);
            s8v brh = *(const s8v*)&WbH[(lrow) * 264 + bo];
            s8v brl = *(const s8v*)&WbL[(lrow) * 264 + bo];
            s8v bzh = *(const s8v*)&WbH[(16 + lrow) * 264 + bo];
            s8v bzl = *(const s8v*)&WbL[(16 + lrow) * 264 + bo];
            s8v bnh = *(const s8v*)&WbH[(32 + lrow) * 264 + bo];
            s8v bnl = *(const s8v*)&WbL[(32 + lrow) * 264 + bo];
            acc_r  = mfma16(ahi, brh, acc_r);
            acc_r  = mfma16(ahi, brl, acc_r);
            acc_r  = mfma16(alo, brh, acc_r);
            acc_z  = mfma16(ahi, bzh, acc_z);
            acc_z  = mfma16(ahi, bzl, acc_z);
            acc_z  = mfma16(alo, bzh, acc_z);
            acc_hn = mfma16(ahi, bnh, acc_hn);
            acc_hn = mfma16(ahi, bnl, acc_hn);
            acc_hn = mfma16(alo, bnh, acc_hn);
        }
        __syncthreads();
        if (c < 3) {
            #pragma unroll
            for (int i = 0; i < 6; ++i) {
                int c16 = i * 256 + tid;
                int row = c16 >> 5, p16 = c16 & 31;
                *(i4v*)&WbH[row * 264 + p16 * 8] = stgH[i];
                *(i4v*)&WbL[row * 264 + p16 * 8] = stgL[i];
            }
            __syncthreads();
        }
    }

    // ---- epilogue.  C layout: col = lane&15, row = (lane>>4)*4 + reg
    const int jcol = j0 + lrow;
    const float bhr = bhh[jcol];
    const float bhz = bhh[1024 + jcol];
    const float bhn = bhh[2048 + jcol];

    if constexpr (MODE == 0) {
        const float bir = bih[jcol];
        const float biz = bih[1024 + jcol];
        const float bin = bih[2048 + jcol];
        #pragma unroll
        for (int reg = 0; reg < 4; ++reg) {
            int brow = m0 + wave * 16 + lk8 * 4 + reg;
            float r  = sigf(acc_r[reg] + bir + bhr);
            float z  = sigf(acc_z[reg] + biz + bhz);
            float nn = tanhf(acc_gn[reg] + bin + r * (acc_hn[reg] + bhn));
            size_t off = (size_t)brow * 1024 + jcol;
            float hold = b2f(hin_hi[off]) + b2f(hin_lo[off]);
            float h = (1.f - z) * nn + z * hold;
            u16 hh = f2b(h);
            hout_hi[off] = hh;
            hout_lo[off] = f2b(h - b2f(hh));
        }
    } else {
        #pragma unroll
        for (int reg = 0; reg < 4; ++reg) {
            int brow = m0 + wave * 16 + lk8 * 4 + reg;
            gh_out[(size_t)brow * 3072 + jcol]        = acc_r[reg] + bhr;
            gh_out[(size_t)brow * 3072 + 1024 + jcol] = acc_z[reg] + bhz;
            gh_out[(size_t)brow * 3072 + 2048 + jcol] = acc_hn[reg] + bhn;
        }
    }
}

// ---------------------------------------------------------------------------
// Fused decoder: per block b (grid 256): gi GEMM (split) + gates -> ns (hi+lo
// in LDS) -> projection (split) accumulated in registers -> FP32 out.
__global__ __launch_bounds__(256, 1) void dec_fused(
    const u16* __restrict__ WihH, const u16* __restrict__ WihL,
    const float* __restrict__ bih,
    const float* __restrict__ xdec,
    const u16* __restrict__ ehi, const u16* __restrict__ elo,
    const float* __restrict__ gh,
    const u16* __restrict__ pWH, const u16* __restrict__ pWL,
    const float* __restrict__ pb,
    float* __restrict__ out)
{
    __shared__ u16 XdH[64 * 72];
    __shared__ u16 XdL[64 * 72];
    __shared__ u16 WiH_[192 * 72];
    __shared__ u16 WiL_[192 * 72];
    __shared__ u16 nsH[64 * 72];
    __shared__ u16 nsL[64 * 72];

    const int tid  = threadIdx.x;
    const int lane = tid & 63;
    const int wave = tid >> 6;
    const int lrow = lane & 15;
    const int lk8  = lane >> 4;
    const int b    = blockIdx.x;

    {   // stage x (fp32 -> hi+lo)
        int row = tid >> 2, q = tid & 3;
        const float* xr = xdec + (size_t)(b * 64 + row) * 63;
        #pragma unroll
        for (int ii = 0; ii < 16; ++ii) {
            int col = q * 16 + ii;
            float v = (col < 63) ? xr[col] : 0.f;
            u16 hh = f2b(v);
            XdH[row * 72 + col] = hh;
            XdL[row * 72 + col] = f2b(v - b2f(hh));
        }
    }

    f4v oacc[4];
    #pragma unroll
    for (int f = 0; f < 4; ++f) oacc[f] = f4v{0.f, 0.f, 0.f, 0.f};

    for (int j0 = 0; j0 < 1024; j0 += 64) {
        // stage Wih chunk: 3 gates x 64 j-rows (hi+lo)
        #pragma unroll
        for (int k = 0; k < 3; ++k) {
            int c = tid + k * 256;           // 0..767
            int r = c >> 2, qq = c & 3;      // r 0..191
            int grow = (r >> 6) * 1024 + j0 + (r & 63);
            const u16* srcH = WihH + (size_t)grow * 64 + qq * 16;
            const u16* srcL = WihL + (size_t)grow * 64 + qq * 16;
            *(i4v*)&WiH_[r * 72 + qq * 16]     = *(const i4v*)srcH;
            *(i4v*)&WiH_[r * 72 + qq * 16 + 8] = *(const i4v*)(srcH + 8);
            *(i4v*)&WiL_[r * 72 + qq * 16]     = *(const i4v*)srcL;
            *(i4v*)&WiL_[r * 72 + qq * 16 + 8] = *(const i4v*)(srcL + 8);
        }
        __syncthreads();   // Wi (and first-iter Xd) ready

        // gi MFMA (split): rows t = wave*16+lrow, cols j0 + jf*16 + n
        f4v ar[4], az[4], an[4];
        #pragma unroll
        for (int jf = 0; jf < 4; ++jf) {
            ar[jf] = f4v{0.f, 0.f, 0.f, 0.f};
            az[jf] = f4v{0.f, 0.f, 0.f, 0.f};
            an[jf] = f4v{0.f, 0.f, 0.f, 0.f};
        }
        #pragma unroll
        for (int ks = 0; ks < 2; ++ks) {
            int ao = ks * 32 + lk8 * 8;
            s8v ah = *(const s8v*)&XdH[(wave * 16 + lrow) * 72 + ao];
            s8v al = *(const s8v*)&XdL[(wave * 16 + lrow) * 72 + ao];
            #pragma unroll
            for (int jf = 0; jf < 4; ++jf) {
                s8v brh = *(const s8v*)&WiH_[(jf * 16 + lrow) * 72 + ao];
                s8v brl = *(const s8v*)&WiL_[(jf * 16 + lrow) * 72 + ao];
                s8v bzh = *(const s8v*)&WiH_[(64 + jf * 16 + lrow) * 72 + ao];
                s8v bzl = *(const s8v*)&WiL_[(64 + jf * 16 + lrow) * 72 + ao];
                s8v bnh = *(const s8v*)&WiH_[(128 + jf * 16 + lrow) * 72 + ao];
                s8v bnl = *(const s8v*)&WiL_[(128 + jf * 16 + lrow) * 72 + ao];
                ar[jf] = mfma16(ah, brh, ar[jf]);
                ar[jf] = mfma16(ah, brl, ar[jf]);
                ar[jf] = mfma16(al, brh, ar[jf]);
                az[jf] = mfma16(ah, bzh, az[jf]);
                az[jf] = mfma16(ah, bzl, az[jf]);
                az[jf] = mfma16(al, bzh, az[jf]);
                an[jf] = mfma16(ah, bnh, an[jf]);
                an[jf] = mfma16(ah, bnl, an[jf]);
                an[jf] = mfma16(al, bnh, an[jf]);
            }
        }

        // gates -> ns (hi+lo) into LDS (C layout -> row-major)
        #pragma unroll
        for (int jf = 0; jf < 4; ++jf) {
            int j = j0 + jf * 16 + lrow;
            float ghr = gh[(size_t)b * 3072 + j];
            float ghz = gh[(size_t)b * 3072 + 1024 + j];
            float ghn = gh[(size_t)b * 3072 + 2048 + j];
            float bir = bih[j];
            float biz = bih[1024 + j];
            float bin = bih[2048 + j];
            size_t eo = (size_t)b * 1024 + j;
            float he = b2f(ehi[eo]) + b2f(elo[eo]);
            #pragma unroll
            for (int reg = 0; reg < 4; ++reg) {
                float r  = sigf(ar[jf][reg] + bir + ghr);
                float z  = sigf(az[jf][reg] + biz + ghz);
                float nn = tanhf(an[jf][reg] + bin + r * ghn);
                float v  = (1.f - z) * nn + z * he;
                u16 hh = f2b(v);
                int lo_i = (wave * 16 + lk8 * 4 + reg) * 72 + jf * 16 + lrow;
                nsH[lo_i] = hh;
                nsL[lo_i] = f2b(v - b2f(hh));
            }
        }
        __syncthreads();   // nsb ready

        // projection partial (split): oacc += ns @ pW[:, j0:j0+64]^T
        #pragma unroll
        for (int ks = 0; ks < 2; ++ks) {
            int ao = ks * 32 + lk8 * 8;
            s8v ah = *(const s8v*)&nsH[(wave * 16 + lrow) * 72 + ao];
            s8v al = *(const s8v*)&nsL[(wave * 16 + lrow) * 72 + ao];
            #pragma unroll
            for (int f = 0; f < 4; ++f) {
                size_t bo = (size_t)(f * 16 + lrow) * 1024 + j0 + ks * 32 + lk8 * 8;
                s8v bh = *(const s8v*)(pWH + bo);
                s8v bl = *(const s8v*)(pWL + bo);
                oacc[f] = mfma16(ah, bh, oacc[f]);
                oacc[f] = mfma16(ah, bl, oacc[f]);
                oacc[f] = mfma16(al, bh, oacc[f]);
            }
        }
        __syncthreads();   // before next iter overwrites Wi / ns
    }

    // epilogue — FP32 stores (reference output dtype is float32)
    #pragma unroll
    for (int f = 0; f < 4; ++f) {
        int o = f * 16 + lrow;
        if (o < 63) {
            float pbv = pb[o];
            #pragma unroll
            for (int reg = 0; reg < 4; ++reg) {
                int t = wave * 16 + lk8 * 4 + reg;
                out[((size_t)(b * 64 + t)) * 63 + o] = oacc[f][reg] + pbv;
            }
        }
    }
}

// ---------------------------------------------------------------------------
extern "C" void kernel_launch(void* const* d_in, const int* in_sizes, int n_in,
                              void* d_out, int out_size, void* d_ws, size_t ws_size,
                              hipStream_t stream)
{
    const float* enc_x = (const float*)d_in[0];
    const float* dec_x = (const float*)d_in[1];
    const float* eWih  = (const float*)d_in[2];
    const float* eWhh  = (const float*)d_in[3];
    const float* ebih  = (const float*)d_in[4];
    const float* ebhh  = (const float*)d_in[5];
    const float* dWih  = (const float*)d_in[6];
    const float* dWhh  = (const float*)d_in[7];
    const float* dbih  = (const float*)d_in[8];
    const float* dbhh  = (const float*)d_in[9];
    const float* pW    = (const float*)d_in[10];
    const float* pb    = (const float*)d_in[11];

    char* ws = (char*)d_ws;
    u16*   H0hi  = (u16*)(ws);                    // 512 KB (256 x 1024 bf16)
    u16*   H0lo  = (u16*)(ws + 524288);
    u16*   H1hi  = (u16*)(ws + 1048576);
    u16*   H1lo  = (u16*)(ws + 1572864);
    float* ghd   = (float*)(ws + 2097152);        // 3 MB (256 x 3072 fp32)
    u16*   eWhhH = (u16*)(ws + 5242880);          // 6 MB each
    u16*   eWhhL = (u16*)(ws + 11534336);
    u16*   dWhhH = (u16*)(ws + 17825792);
    u16*   dWhhL = (u16*)(ws + 24117248);
    u16*   eWihH = (u16*)(ws + 30408704);         // 384 KB each (3072 x 64)
    u16*   eWihL = (u16*)(ws + 30801920);
    u16*   dWihH = (u16*)(ws + 31195136);
    u16*   dWihL = (u16*)(ws + 31588352);
    u16*   pWH   = (u16*)(ws + 31981568);         // 128 KB each (64 x 1024)
    u16*   pWL   = (u16*)(ws + 32112640);

    // one-time fp32 -> bf16 hi+lo weight conversions
    conv_split<<<dim3(4096), dim3(256), 0, stream>>>(eWhh, eWhhH, eWhhL, 3145728);
    conv_split<<<dim3(4096), dim3(256), 0, stream>>>(dWhh, dWhhH, dWhhL, 3145728);
    conv_wih_split_pad<<<dim3(768), dim3(256), 0, stream>>>(eWih, eWihH, eWihL);
    conv_wih_split_pad<<<dim3(768), dim3(256), 0, stream>>>(dWih, dWihH, dWihL);
    conv_pw_split_pad<<<dim3(256), dim3(256), 0, stream>>>(pW, pWH, pWL);

    // h0 = 0 (H0hi + H0lo contiguous 1 MB)
    zero_ws<<<dim3(256), dim3(256), 0, stream>>>((i4v*)ws, 65536);

    // encoder recurrence: 128 sequential steps, ping-pong h buffers
    for (int s = 0; s < 128; ++s) {
        const u16* ihi = (s & 1) ? H1hi : H0hi;
        const u16* ilo = (s & 1) ? H1lo : H0lo;
        u16* ohi = (s & 1) ? H0hi : H1hi;
        u16* olo = (s & 1) ? H0lo : H1lo;
        gru_gemm<0><<<dim3(256), dim3(256), 0, stream>>>(
            eWhhH, eWhhL, eWihH, eWihL, ebih, ebhh, enc_x, s,
            ihi, ilo, ohi, olo, nullptr);
    }
    // final enc_h lives in H0

    // gh_dec = enc_h @ dec_Whh^T + dec_bhh
    gru_gemm<1><<<dim3(256), dim3(256), 0, stream>>>(
        dWhhH, dWhhL, nullptr, nullptr, nullptr, dbhh, nullptr, 0,
        H0hi, H0lo, nullptr, nullptr, ghd);

    // fused decoder gates + projection -> fp32 out
    dec_fused<<<dim3(256), dim3(256), 0, stream>>>(
        dWihH, dWihL, dbih, dec_x, H0hi, H0lo, ghd, pWH, pWL, pb, (float*)d_out);
}